// Round 11
// baseline (109.734 us; speedup 1.0000x reference)
//
#include <hip/hip_runtime.h>
#include <hip/hip_bf16.h>

typedef unsigned short u16;
typedef __bf16 bf16x8 __attribute__((ext_vector_type(8)));
typedef float  f32x16 __attribute__((ext_vector_type(16)));

#define BB    4
#define SS    4096
#define DD    1024
#define EE    8
#define M_TOT (BB*SS)   /* 16384 */
#define N_TOT DD        /* 1024  */
#define K_TOT DD        /* 1024  */

#define BM 256
#define BN 128
#define BK 64
#define NT (K_TOT/BK)   /* 16 K-tiles */

#define GATE_BLOCKS 1024   /* 16 tokens per block, 4 per wave */

__device__ __forceinline__ u16 f2bf(float f) {
  unsigned u = __builtin_bit_cast(unsigned, f);
  u += 0x7fffu + ((u >> 16) & 1u);          // round-to-nearest-even
  return (u16)(u >> 16);
}

__device__ __forceinline__ void stage16(u16* lds, const u16* g) {
  __builtin_amdgcn_global_load_lds((const __attribute__((address_space(1))) void*)g,
                                   (__attribute__((address_space(3))) void*)lds,
                                   16, 0, 0);
}

// ---------------------------------------------------------------------------
// Kernel 1: gate (fp32, exact) + token f32->bf16 convert, plus weight convert.
// (unchanged — measured ~92% of achievable HBM BW)
// ---------------------------------------------------------------------------
__global__ __launch_bounds__(256) void gate_convert_kernel(
    const float* __restrict__ tokens, const float* __restrict__ gate_w,
    const float* __restrict__ w0,     const float* __restrict__ w1,
    u16* __restrict__ tok_bf, u16* __restrict__ w0_bf, u16* __restrict__ w1_bf,
    float* __restrict__ scales)
{
  const int bid = blockIdx.x;
  const int tid = threadIdx.x;

  if (bid < GATE_BLOCKS) {
    __shared__ float gwT[EE][DD];       // 32 KB, transposed gate weights
    #pragma unroll
    for (int r = 0; r < 4; ++r) {
      const int d = r * 256 + tid;      // coalesced: lanes 32B apart
      float4 a = *(const float4*)&gate_w[d * EE];
      float4 b = *(const float4*)&gate_w[d * EE + 4];
      gwT[0][d] = a.x; gwT[1][d] = a.y; gwT[2][d] = a.z; gwT[3][d] = a.w;
      gwT[4][d] = b.x; gwT[5][d] = b.y; gwT[6][d] = b.z; gwT[7][d] = b.w;
    }
    __syncthreads();

    const int lane = tid & 63, wid = tid >> 6;
    const int tbase = (bid * 4 + wid) * 4;          // 4 tokens per wave

    float lg[4][EE];
    #pragma unroll
    for (int t = 0; t < 4; ++t)
      #pragma unroll
      for (int e = 0; e < EE; ++e) lg[t][e] = 0.0f;

    #pragma unroll
    for (int c = 0; c < 4; ++c) {
      const int d = c * 256 + lane * 4;
      float4 gw[EE];
      #pragma unroll
      for (int e = 0; e < EE; ++e)
        gw[e] = *(const float4*)&gwT[e][d];         // ds_read_b128, lanes 16B apart
      #pragma unroll
      for (int t = 0; t < 4; ++t) {
        const size_t off = (size_t)(tbase + t) * DD + d;
        float4 v = *(const float4*)(tokens + off);
        *(ushort4*)(tok_bf + off) =
            make_ushort4(f2bf(v.x), f2bf(v.y), f2bf(v.z), f2bf(v.w));
        #pragma unroll
        for (int e = 0; e < EE; ++e)
          lg[t][e] = fmaf(v.w, gw[e].w, fmaf(v.z, gw[e].z,
                     fmaf(v.y, gw[e].y, fmaf(v.x, gw[e].x, lg[t][e]))));
      }
    }

    // Expert-splitting butterfly reduce, then shuffle softmax/top-2.
    const int b0 = lane & 1, b1 = (lane >> 1) & 1, b2 = (lane >> 2) & 1;
    const int E  = b0 * 4 + (lane & 2) + b2;

    #pragma unroll
    for (int t = 0; t < 4; ++t) {
      float n0[4], n1[2], rr;
      #pragma unroll
      for (int i = 0; i < 4; ++i) {
        float send = b0 ? lg[t][i] : lg[t][i + 4];
        float keep = b0 ? lg[t][i + 4] : lg[t][i];
        n0[i] = keep + __shfl_xor(send, 1, 64);
      }
      #pragma unroll
      for (int i = 0; i < 2; ++i) {
        float send = b1 ? n0[i] : n0[i + 2];
        float keep = b1 ? n0[i + 2] : n0[i];
        n1[i] = keep + __shfl_xor(send, 2, 64);
      }
      {
        float send = b2 ? n1[0] : n1[1];
        float keep = b2 ? n1[1] : n1[0];
        rr = keep + __shfl_xor(send, 4, 64);
      }
      rr += __shfl_xor(rr, 8, 64);
      rr += __shfl_xor(rr, 16, 64);
      rr += __shfl_xor(rr, 32, 64);

      float m = rr;
      m = fmaxf(m, __shfl_xor(m, 1, 64));
      m = fmaxf(m, __shfl_xor(m, 2, 64));
      m = fmaxf(m, __shfl_xor(m, 4, 64));
      float p = __expf(rr - m);
      float s = p;
      s += __shfl_xor(s, 1, 64);
      s += __shfl_xor(s, 2, 64);
      s += __shfl_xor(s, 4, 64);

      int cnt = 0;
      #pragma unroll
      for (int k = 1; k < 8; ++k) {
        float Lo = __shfl_xor(rr, k, 64);
        const int Eo = E ^ ((k & 1) * 4 + (k & 2) + ((k >> 2) & 1));
        cnt += (Lo > rr || (Lo == rr && Eo < E)) ? 1 : 0;
      }
      if (lane < 8) {
        const float w = p / s;
        if (E == 0) scales[(tbase + t) * 2 + 0] = (cnt == 0) ? w : 0.0f;
        if (E == 1) scales[(tbase + t) * 2 + 1] = (cnt == 1) ? w : 0.0f;
      }
    }
  } else {
    const int wb = bid - GATE_BLOCKS;            // 0..2047
    const float* src = (wb < 1024) ? w0 : w1;
    u16*        dst = (wb < 1024) ? w0_bf : w1_bf;
    const int base = (wb & 1023) * 1024 + tid * 4;
    float4 v = *(const float4*)(src + base);
    *(ushort4*)(dst + base) =
        make_ushort4(f2bf(v.x), f2bf(v.y), f2bf(v.z), f2bf(v.w));
  }
}

// ---------------------------------------------------------------------------
// Kernel 2: fused dual-GEMM, v6: r8 structure + 32x32x16 MFMA.
// 32x32x16 runs at 2495 TF (99.8% peak, m119) vs 2075 for 16x16x32, and
// halves MFMA instruction count (32/wave/tile) at IDENTICAL LDS read bytes
// (24 x ds_read_b128/wave/tile, same swizzle algebra).
// Protocol (r8, best measured): no manual lgkm (compiler counted waits);
// per tile: {read afr+b0f upfront | STAGE_A' | 8 MFMA | vm(4)+BAR |
// read b1f | STAGE_B0' | 8 MFMA | STAGE_B1' | 8 MFMA | 8 MFMA | vm(2)+BAR}.
// A/B fragment layout (32x32x16): lane&31 = row/col, lane>>5 = K-half,
// 8 contiguous K elems per lane.  C/D: col=lane&31,
// row=(reg&3)+8*(reg>>2)+4*(lane>>5)  [verified m74/m101].
// ---------------------------------------------------------------------------
__global__ __launch_bounds__(512, 2) void moe_gemm_kernel(
    const u16* __restrict__ A,    // [M,K] bf16
    const u16* __restrict__ Bw0,  // [N,K] bf16 (w0 row-major = B^T)
    const u16* __restrict__ Bw1,  // [N,K] bf16
    const float* __restrict__ bias0, const float* __restrict__ bias1,
    const float* __restrict__ scales, // [M,2]
    float* __restrict__ out)      // [M,N] f32
{
  __shared__ u16 lA [2][BM * BK];   // 64 KiB
  __shared__ u16 lB0[2][BN * BK];   // 32 KiB
  __shared__ u16 lB1[2][BN * BK];   // 32 KiB

  const int tid = threadIdx.x;

  // bijective XCD swizzle: 512 blocks, 8 XCDs, 64 blocks/XCD chunk.
  const int wgid = (blockIdx.x & 7) * 64 + (blockIdx.x >> 3);
  const int bm = wgid >> 3, bn = wgid & 7;    // bn fastest: XCD shares A panels
  const int m0 = bm * BM, n0 = bn * BN;

  const int lane = tid & 63;
  const int wid  = tid >> 6;                  // 0..7
  const int wm = wid >> 1, wn = wid & 1;      // 4M x 2N wave grid
  const int r32 = lane & 31;                  // fragment row/col
  const int kh  = lane >> 5;                  // K-half (0..1)
  const int r32h = (r32 >> 1) & 7;            // read-swizzle term

  const int schunk = ((tid & 7) ^ ((tid >> 4) & 7)) * 8;
  const u16* gA  = A   + (size_t)(m0 + (tid >> 3)) * K_TOT + schunk;
  const u16* gB0 = Bw0 + (size_t)(n0 + (tid >> 3)) * K_TOT + schunk;
  const u16* gB1 = Bw1 + (size_t)(n0 + (tid >> 3)) * K_TOT + schunk;

#define STAGE_A(buf, c, ko)  stage16(&lA [buf][(c)*4096 + tid*8], gA  + (size_t)(c)*64*K_TOT + (ko))
#define STAGE_B0(buf, c, ko) stage16(&lB0[buf][(c)*4096 + tid*8], gB0 + (size_t)(c)*64*K_TOT + (ko))
#define STAGE_B1(buf, c, ko) stage16(&lB1[buf][(c)*4096 + tid*8], gB1 + (size_t)(c)*64*K_TOT + (ko))

  // 32x32x16 fragment: row = rowbase + r32, K-chunk = ks*2 + kh (8 elems),
  // physical chunk XOR'd with (row>>1)&7 (rowbases are multiples of 32).
#define FRAG32(L, buf, rowbase, ks) \
  (*(const bf16x8*)&L[buf][((rowbase) + r32) * BK + ((((ks)*2 + kh)) ^ r32h) * 8])

#define BAR()        __builtin_amdgcn_s_barrier()
#define WAIT_VM(N)   asm volatile("s_waitcnt vmcnt(" #N ")" ::: "memory")

  // 8 MFMA over ks in [KS0, KS0+1], both i,j quadrants.
#define BATCH8(ACC, AF, BF, KS0) do {                                         \
    __builtin_amdgcn_s_setprio(1);                                            \
    _Pragma("unroll")                                                         \
    for (int ks = (KS0); ks < (KS0) + 2; ++ks)                                \
      _Pragma("unroll")                                                       \
      for (int i = 0; i < 2; ++i)                                             \
        _Pragma("unroll")                                                     \
        for (int j = 0; j < 2; ++j)                                           \
          ACC[i][j] = __builtin_amdgcn_mfma_f32_32x32x16_bf16(                \
              AF[i][ks], BF[j][ks], ACC[i][j], 0, 0, 0);                      \
    __builtin_amdgcn_s_setprio(0);                                            \
  } while (0)

  f32x16 acc0[2][2] = {};
  f32x16 acc1[2][2] = {};
  bf16x8 afr[2][4], b0f[2][4], b1f[2][4];   // static-indexed banks (rule 20)

  // Prologue: stage K-tile 0 (FIFO: A x4, B0 x2, B1 x2); wait A+B0,
  // leave B1 in flight; barrier.
  STAGE_A(0, 0, 0); STAGE_A(0, 1, 0); STAGE_A(0, 2, 0); STAGE_A(0, 3, 0);
  STAGE_B0(0, 0, 0); STAGE_B0(0, 1, 0);
  STAGE_B1(0, 0, 0); STAGE_B1(0, 1, 0);
  WAIT_VM(2);
  BAR();

  int cur = 0;
  // Steady tiles 0..NT-2 (each prefetches tile t+1).
  for (int t = 0; t < NT - 1; ++t) {
    const int nxt = cur ^ 1;
    const size_t ko = (size_t)(t + 1) * BK;

    // upfront reads: all A frags, all B0 frags (16 x ds_read_b128)
    #pragma unroll
    for (int i = 0; i < 2; ++i)
      #pragma unroll
      for (int ks = 0; ks < 4; ++ks)
        afr[i][ks] = FRAG32(lA, cur, wm * 64 + i * 32, ks);
    #pragma unroll
    for (int j = 0; j < 2; ++j)
      #pragma unroll
      for (int ks = 0; ks < 4; ++ks)
        b0f[j][ks] = FRAG32(lB0, cur, wn * 64 + j * 32, ks);
    STAGE_A(nxt, 0, ko); STAGE_A(nxt, 1, ko); STAGE_A(nxt, 2, ko); STAGE_A(nxt, 3, ko);

    BATCH8(acc0, afr, b0f, 0);      // e0 ks 0-1 (counted lgkm on first 8 only)
    WAIT_VM(4);                     // old B1[cur] landed; 4 new A' in flight
    BAR();

    #pragma unroll
    for (int j = 0; j < 2; ++j)
      #pragma unroll
      for (int ks = 0; ks < 4; ++ks)
        b1f[j][ks] = FRAG32(lB1, cur, wn * 64 + j * 32, ks);
    STAGE_B0(nxt, 0, ko); STAGE_B0(nxt, 1, ko);

    BATCH8(acc0, afr, b0f, 2);      // e0 ks 2-3, b1 reads overlap
    STAGE_B1(nxt, 0, ko); STAGE_B1(nxt, 1, ko);
    BATCH8(acc1, afr, b1f, 0);      // e1 ks 0-1
    BATCH8(acc1, afr, b1f, 2);      // e1 ks 2-3

    WAIT_VM(2);                     // A'+B0' landed; B1' stays in flight
    BAR();
    cur = nxt;
  }

  // Peeled last tile (no prefetch): drain B1 fully before b1 reads.
  {
    #pragma unroll
    for (int i = 0; i < 2; ++i)
      #pragma unroll
      for (int ks = 0; ks < 4; ++ks)
        afr[i][ks] = FRAG32(lA, cur, wm * 64 + i * 32, ks);
    #pragma unroll
    for (int j = 0; j < 2; ++j)
      #pragma unroll
      for (int ks = 0; ks < 4; ++ks)
        b0f[j][ks] = FRAG32(lB0, cur, wn * 64 + j * 32, ks);
    BATCH8(acc0, afr, b0f, 0);
    WAIT_VM(0);
    BAR();
    #pragma unroll
    for (int j = 0; j < 2; ++j)
      #pragma unroll
      for (int ks = 0; ks < 4; ++ks)
        b1f[j][ks] = FRAG32(lB1, cur, wn * 64 + j * 32, ks);
    BATCH8(acc0, afr, b0f, 2);
    BATCH8(acc1, afr, b1f, 0);
    BATCH8(acc1, afr, b1f, 2);
  }

  // Scales broadcast: reuse lA as 512-float buffer (K-loop fully retired).
  BAR();
  float* sS = (float*)&lA[0][0];
  sS[tid] = scales[m0 * 2 + tid];   // 256 rows x {s0,s1}
  BAR();

  // Epilogue: out = s0*silu(acc0+b0) + s1*silu(acc1+b1)
  // C/D: col = lane&31, row = (reg&3) + 8*(reg>>2) + 4*kh.
  float bb0[2], bb1[2];
  #pragma unroll
  for (int j = 0; j < 2; ++j) {
    const int col = n0 + wn * 64 + j * 32 + r32;
    bb0[j] = bias0[col];
    bb1[j] = bias1[col];
  }
  #pragma unroll
  for (int i = 0; i < 2; ++i) {
    #pragma unroll
    for (int reg = 0; reg < 16; ++reg) {
      const int lrow = (reg & 3) + 8 * (reg >> 2) + 4 * kh;   // 0..31
      const int rl   = wm * 64 + i * 32 + lrow;               // row in block
      const float s0 = sS[rl * 2 + 0];
      const float s1 = sS[rl * 2 + 1];
      float* orow = out + (size_t)(m0 + rl) * N_TOT + n0 + wn * 64;
      #pragma unroll
      for (int j = 0; j < 2; ++j) {
        const float v0 = acc0[i][j][reg] + bb0[j];
        const float v1 = acc1[i][j][reg] + bb1[j];
        const float g0 = v0 / (1.0f + __expf(-v0));
        const float g1 = v1 / (1.0f + __expf(-v1));
        orow[j * 32 + r32] = s0 * g0 + s1 * g1;
      }
    }
  }
#undef STAGE_A
#undef STAGE_B0
#undef STAGE_B1
#undef FRAG32
#undef BAR
#undef WAIT_VM
#undef BATCH8
}

// ---------------------------------------------------------------------------
extern "C" void kernel_launch(void* const* d_in, const int* in_sizes, int n_in,
                              void* d_out, int out_size, void* d_ws, size_t ws_size,
                              hipStream_t stream)
{
  const float* tokens = (const float*)d_in[0];
  const float* gate_w = (const float*)d_in[1];
  const float* w0     = (const float*)d_in[2];
  const float* b0     = (const float*)d_in[3];
  const float* w1     = (const float*)d_in[4];
  const float* b1     = (const float*)d_in[5];
  float* out = (float*)d_out;

  char* ws = (char*)d_ws;
  u16* tok_bf = (u16*)ws;                                               // 32 MB
  u16* w0_bf  = (u16*)(ws + (size_t)M_TOT * K_TOT * 2);                 //  2 MB
  u16* w1_bf  = (u16*)(ws + (size_t)M_TOT * K_TOT * 2 + (size_t)N_TOT * K_TOT * 2);
  float* scales = (float*)(ws + (size_t)M_TOT * K_TOT * 2 + (size_t)2 * N_TOT * K_TOT * 2);

  gate_convert_kernel<<<GATE_BLOCKS + 2048, 256, 0, stream>>>(
      tokens, gate_w, w0, w1, tok_bf, w0_bf, w1_bf, scales);

  moe_gemm_kernel<<<(M_TOT/BM) * (N_TOT/BN), 512, 0, stream>>>(
      tok_bf, w0_bf, w1_bf, b0, b1, scales, out);
}

// Round 12
// 100.318 us; speedup vs baseline: 1.0939x; 1.0939x over previous
//
#include <hip/hip_runtime.h>
#include <hip/hip_bf16.h>

typedef unsigned short u16;
typedef __bf16 bf16x8 __attribute__((ext_vector_type(8)));
typedef float  f32x4  __attribute__((ext_vector_type(4)));

#define BB    4
#define SS    4096
#define DD    1024
#define EE    8
#define M_TOT (BB*SS)   /* 16384 */
#define N_TOT DD        /* 1024  */
#define K_TOT DD        /* 1024  */

#define BM 256
#define BN 128
#define BK 64
#define NT (K_TOT/BK)   /* 16 K-tiles */

#define GATE_BLOCKS 1024   /* 16 tokens per block, 4 per wave */

__device__ __forceinline__ u16 f2bf(float f) {
  unsigned u = __builtin_bit_cast(unsigned, f);
  u += 0x7fffu + ((u >> 16) & 1u);          // round-to-nearest-even
  return (u16)(u >> 16);
}

__device__ __forceinline__ void stage16(u16* lds, const u16* g) {
  __builtin_amdgcn_global_load_lds((const __attribute__((address_space(1))) void*)g,
                                   (__attribute__((address_space(3))) void*)lds,
                                   16, 0, 0);
}

// ---------------------------------------------------------------------------
// Kernel 1: gate (fp32, exact) + token f32->bf16 convert, plus weight convert.
// (unchanged — measured ~92% of achievable HBM BW)
// ---------------------------------------------------------------------------
__global__ __launch_bounds__(256) void gate_convert_kernel(
    const float* __restrict__ tokens, const float* __restrict__ gate_w,
    const float* __restrict__ w0,     const float* __restrict__ w1,
    u16* __restrict__ tok_bf, u16* __restrict__ w0_bf, u16* __restrict__ w1_bf,
    float* __restrict__ scales)
{
  const int bid = blockIdx.x;
  const int tid = threadIdx.x;

  if (bid < GATE_BLOCKS) {
    __shared__ float gwT[EE][DD];       // 32 KB, transposed gate weights
    #pragma unroll
    for (int r = 0; r < 4; ++r) {
      const int d = r * 256 + tid;      // coalesced: lanes 32B apart
      float4 a = *(const float4*)&gate_w[d * EE];
      float4 b = *(const float4*)&gate_w[d * EE + 4];
      gwT[0][d] = a.x; gwT[1][d] = a.y; gwT[2][d] = a.z; gwT[3][d] = a.w;
      gwT[4][d] = b.x; gwT[5][d] = b.y; gwT[6][d] = b.z; gwT[7][d] = b.w;
    }
    __syncthreads();

    const int lane = tid & 63, wid = tid >> 6;
    const int tbase = (bid * 4 + wid) * 4;          // 4 tokens per wave

    float lg[4][EE];
    #pragma unroll
    for (int t = 0; t < 4; ++t)
      #pragma unroll
      for (int e = 0; e < EE; ++e) lg[t][e] = 0.0f;

    #pragma unroll
    for (int c = 0; c < 4; ++c) {
      const int d = c * 256 + lane * 4;
      float4 gw[EE];
      #pragma unroll
      for (int e = 0; e < EE; ++e)
        gw[e] = *(const float4*)&gwT[e][d];         // ds_read_b128, lanes 16B apart
      #pragma unroll
      for (int t = 0; t < 4; ++t) {
        const size_t off = (size_t)(tbase + t) * DD + d;
        float4 v = *(const float4*)(tokens + off);
        *(ushort4*)(tok_bf + off) =
            make_ushort4(f2bf(v.x), f2bf(v.y), f2bf(v.z), f2bf(v.w));
        #pragma unroll
        for (int e = 0; e < EE; ++e)
          lg[t][e] = fmaf(v.w, gw[e].w, fmaf(v.z, gw[e].z,
                     fmaf(v.y, gw[e].y, fmaf(v.x, gw[e].x, lg[t][e]))));
      }
    }

    // Expert-splitting butterfly reduce, then shuffle softmax/top-2.
    const int b0 = lane & 1, b1 = (lane >> 1) & 1, b2 = (lane >> 2) & 1;
    const int E  = b0 * 4 + (lane & 2) + b2;

    #pragma unroll
    for (int t = 0; t < 4; ++t) {
      float n0[4], n1[2], rr;
      #pragma unroll
      for (int i = 0; i < 4; ++i) {
        float send = b0 ? lg[t][i] : lg[t][i + 4];
        float keep = b0 ? lg[t][i + 4] : lg[t][i];
        n0[i] = keep + __shfl_xor(send, 1, 64);
      }
      #pragma unroll
      for (int i = 0; i < 2; ++i) {
        float send = b1 ? n0[i] : n0[i + 2];
        float keep = b1 ? n0[i + 2] : n0[i];
        n1[i] = keep + __shfl_xor(send, 2, 64);
      }
      {
        float send = b2 ? n1[0] : n1[1];
        float keep = b2 ? n1[1] : n1[0];
        rr = keep + __shfl_xor(send, 4, 64);
      }
      rr += __shfl_xor(rr, 8, 64);
      rr += __shfl_xor(rr, 16, 64);
      rr += __shfl_xor(rr, 32, 64);

      float m = rr;
      m = fmaxf(m, __shfl_xor(m, 1, 64));
      m = fmaxf(m, __shfl_xor(m, 2, 64));
      m = fmaxf(m, __shfl_xor(m, 4, 64));
      float p = __expf(rr - m);
      float s = p;
      s += __shfl_xor(s, 1, 64);
      s += __shfl_xor(s, 2, 64);
      s += __shfl_xor(s, 4, 64);

      int cnt = 0;
      #pragma unroll
      for (int k = 1; k < 8; ++k) {
        float Lo = __shfl_xor(rr, k, 64);
        const int Eo = E ^ ((k & 1) * 4 + (k & 2) + ((k >> 2) & 1));
        cnt += (Lo > rr || (Lo == rr && Eo < E)) ? 1 : 0;
      }
      if (lane < 8) {
        const float w = p / s;
        if (E == 0) scales[(tbase + t) * 2 + 0] = (cnt == 0) ? w : 0.0f;
        if (E == 1) scales[(tbase + t) * 2 + 1] = (cnt == 1) ? w : 0.0f;
      }
    }
  } else {
    const int wb = bid - GATE_BLOCKS;            // 0..2047
    const float* src = (wb < 1024) ? w0 : w1;
    u16*        dst = (wb < 1024) ? w0_bf : w1_bf;
    const int base = (wb & 1023) * 1024 + tid * 4;
    float4 v = *(const float4*)(src + base);
    *(ushort4*)(dst + base) =
        make_ushort4(f2bf(v.x), f2bf(v.y), f2bf(v.z), f2bf(v.w));
  }
}

// ---------------------------------------------------------------------------
// Kernel 2: fused dual-GEMM, v7: r8 base (best, 875 TF) + enforced
// fine-grained DS_READ<->MFMA interleave.
//
// Model (r11 audit): all prior variants = 5888 cyc/K-tile/CU = MFMA 2483 +
// LDS 3083 + sync, STRICTLY ADDITIVE (MfmaUtil 33-37% == 2483/5888 every
// round).  Cause: compiler hoists all fragment reads into one block
// (VGPR=120 shows 16 reads live), so the CU's 128 reads drain with the
// matrix pipe idle, then all waves MFMA with the LDS pipe idle.
// Fix: 8-read quanta, each MFMA batch waits only its own quantum
// (counted lgkm by compiler), next quantum drains UNDER the batch;
// sched_group_barrier pins stop re-hoisting:
//   region1: q1(afA,b0A) q2(afB,b0B) stageA'x4 batch1(acc0,kk0)
//            SGB: DS16, VMEM4, MFMA16;  vm(4) BAR
//   region2: q3(b1A,b1B) stageB0' batch2(acc0,kk1) stageB1'
//            batch3(acc1,kk0) batch4(acc1,kk1)
//            SGB: DS8, VMEM2, MFMA16, VMEM2, MFMA16, MFMA16;  vm(2) BAR
// vmcnt protocol identical to r8 (B1' always in flight across boundary).
// ---------------------------------------------------------------------------
__global__ __launch_bounds__(512, 2) void moe_gemm_kernel(
    const u16* __restrict__ A,    // [M,K] bf16
    const u16* __restrict__ Bw0,  // [N,K] bf16 (w0 row-major = B^T)
    const u16* __restrict__ Bw1,  // [N,K] bf16
    const float* __restrict__ bias0, const float* __restrict__ bias1,
    const float* __restrict__ scales, // [M,2]
    float* __restrict__ out)      // [M,N] f32
{
  __shared__ u16 lA [2][BM * BK];   // 64 KiB
  __shared__ u16 lB0[2][BN * BK];   // 32 KiB
  __shared__ u16 lB1[2][BN * BK];   // 32 KiB

  const int tid = threadIdx.x;

  // bijective XCD swizzle: 512 blocks, 8 XCDs, 64 blocks/XCD chunk.
  const int wgid = (blockIdx.x & 7) * 64 + (blockIdx.x >> 3);
  const int bm = wgid >> 3, bn = wgid & 7;    // bn fastest: XCD shares A panels
  const int m0 = bm * BM, n0 = bn * BN;

  const int lane = tid & 63;
  const int wid  = tid >> 6;                  // 0..7
  const int wm = wid >> 1, wn = wid & 1;      // 4M x 2N wave grid
  const int fr = lane & 15, fq = lane >> 4;
  const int frh = fr >> 1;                    // read-swizzle term

  const int schunk = ((tid & 7) ^ ((tid >> 4) & 7)) * 8;
  const u16* gA  = A   + (size_t)(m0 + (tid >> 3)) * K_TOT + schunk;
  const u16* gB0 = Bw0 + (size_t)(n0 + (tid >> 3)) * K_TOT + schunk;
  const u16* gB1 = Bw1 + (size_t)(n0 + (tid >> 3)) * K_TOT + schunk;

#define STAGE_A(buf, c, ko)  stage16(&lA [buf][(c)*4096 + tid*8], gA  + (size_t)(c)*64*K_TOT + (ko))
#define STAGE_B0(buf, c, ko) stage16(&lB0[buf][(c)*4096 + tid*8], gB0 + (size_t)(c)*64*K_TOT + (ko))
#define STAGE_B1(buf, c, ko) stage16(&lB1[buf][(c)*4096 + tid*8], gB1 + (size_t)(c)*64*K_TOT + (ko))

#define FRAG(L, buf, rowbase, kk) \
  (*(const bf16x8*)&L[buf][((rowbase) + fr) * BK + ((((kk) << 2) | fq) ^ frh) * 8])

#define BAR()        __builtin_amdgcn_s_barrier()
#define WAIT_VM(N)   asm volatile("s_waitcnt vmcnt(" #N ")" ::: "memory")
#define SGB(m, n)    __builtin_amdgcn_sched_group_barrier((m), (n), 0)

#define MFMA16(ACC, AF, BF) do {                                              \
    __builtin_amdgcn_s_setprio(1);                                            \
    _Pragma("unroll")                                                         \
    for (int i = 0; i < 4; ++i)                                               \
      _Pragma("unroll")                                                       \
      for (int j = 0; j < 4; ++j)                                             \
        ACC[i][j] = __builtin_amdgcn_mfma_f32_16x16x32_bf16(AF[i], BF[j],     \
                                                            ACC[i][j], 0,0,0);\
    __builtin_amdgcn_s_setprio(0);                                            \
  } while (0)

  f32x4 acc0[4][4] = {};
  f32x4 acc1[4][4] = {};
  bf16x8 afA[4], afB[4], b0A[4], b0B[4], b1A[4], b1B[4];  // named banks

  // Prologue: stage K-tile 0 (FIFO: A x4, B0 x2, B1 x2); wait A+B0,
  // leave B1 in flight (steady-state invariant); barrier.
  STAGE_A(0, 0, 0); STAGE_A(0, 1, 0); STAGE_A(0, 2, 0); STAGE_A(0, 3, 0);
  STAGE_B0(0, 0, 0); STAGE_B0(0, 1, 0);
  STAGE_B1(0, 0, 0); STAGE_B1(0, 1, 0);
  WAIT_VM(2);
  BAR();

  int cur = 0;
  // Steady tiles 0..NT-2 (each prefetches tile t+1).
  for (int t = 0; t < NT - 1; ++t) {
    const int nxt = cur ^ 1;
    const size_t ko = (size_t)(t + 1) * BK;

    // ===== region 1: q1, q2, stage A', batch1 =====
    #pragma unroll
    for (int i = 0; i < 4; ++i) afA[i] = FRAG(lA,  cur, wm * 64 + i * 16, 0);
    #pragma unroll
    for (int j = 0; j < 4; ++j) b0A[j] = FRAG(lB0, cur, wn * 64 + j * 16, 0);
    #pragma unroll
    for (int i = 0; i < 4; ++i) afB[i] = FRAG(lA,  cur, wm * 64 + i * 16, 1);
    #pragma unroll
    for (int j = 0; j < 4; ++j) b0B[j] = FRAG(lB0, cur, wn * 64 + j * 16, 1);
    STAGE_A(nxt, 0, ko); STAGE_A(nxt, 1, ko); STAGE_A(nxt, 2, ko); STAGE_A(nxt, 3, ko);
    MFMA16(acc0, afA, b0A);          // waits only q1 (counted lgkm); q2 drains under it
    SGB(0x100, 16);                  // 16 ds_read (q1+q2)
    SGB(0x010, 4);                   // 4 global_load_lds (A')
    SGB(0x008, 16);                  // batch1
    WAIT_VM(4);                      // old B1[cur] landed; 4 A' stay in flight
    BAR();

    // ===== region 2: q3, stages, batches 2-4 =====
    #pragma unroll
    for (int j = 0; j < 4; ++j) b1A[j] = FRAG(lB1, cur, wn * 64 + j * 16, 0);
    #pragma unroll
    for (int j = 0; j < 4; ++j) b1B[j] = FRAG(lB1, cur, wn * 64 + j * 16, 1);
    STAGE_B0(nxt, 0, ko); STAGE_B0(nxt, 1, ko);
    MFMA16(acc0, afB, b0B);          // operands from region 1: no wait; q3 drains under it
    STAGE_B1(nxt, 0, ko); STAGE_B1(nxt, 1, ko);
    MFMA16(acc1, afA, b1A);          // waits half of q3 (counted)
    MFMA16(acc1, afB, b1B);
    SGB(0x100, 8);                   // q3
    SGB(0x010, 2);                   // B0'
    SGB(0x008, 16);                  // batch2
    SGB(0x010, 2);                   // B1'
    SGB(0x008, 16);                  // batch3
    SGB(0x008, 16);                  // batch4
    WAIT_VM(2);                      // A'+B0' landed; B1' stays in flight
    BAR();
    cur = nxt;
  }

  // Peeled last tile (no prefetch): drain B1 fully before b1 reads.
  {
    #pragma unroll
    for (int i = 0; i < 4; ++i) afA[i] = FRAG(lA,  cur, wm * 64 + i * 16, 0);
    #pragma unroll
    for (int j = 0; j < 4; ++j) b0A[j] = FRAG(lB0, cur, wn * 64 + j * 16, 0);
    #pragma unroll
    for (int i = 0; i < 4; ++i) afB[i] = FRAG(lA,  cur, wm * 64 + i * 16, 1);
    #pragma unroll
    for (int j = 0; j < 4; ++j) b0B[j] = FRAG(lB0, cur, wn * 64 + j * 16, 1);
    MFMA16(acc0, afA, b0A);
    SGB(0x100, 16); SGB(0x008, 16);
    WAIT_VM(0);
    BAR();

    #pragma unroll
    for (int j = 0; j < 4; ++j) b1A[j] = FRAG(lB1, cur, wn * 64 + j * 16, 0);
    #pragma unroll
    for (int j = 0; j < 4; ++j) b1B[j] = FRAG(lB1, cur, wn * 64 + j * 16, 1);
    MFMA16(acc0, afB, b0B);
    MFMA16(acc1, afA, b1A);
    MFMA16(acc1, afB, b1B);
    SGB(0x100, 8); SGB(0x008, 16); SGB(0x008, 16); SGB(0x008, 16);
  }

  // Epilogue: out = s0*silu(acc0+b0) + s1*silu(acc1+b1)
  float bb0[4], bb1[4];
  #pragma unroll
  for (int j = 0; j < 4; ++j) {
    const int col = n0 + wn * 64 + j * 16 + fr;
    bb0[j] = bias0[col];
    bb1[j] = bias1[col];
  }
  #pragma unroll
  for (int i = 0; i < 4; ++i) {
    #pragma unroll
    for (int r = 0; r < 4; ++r) {
      const int grow = m0 + wm * 64 + i * 16 + fq * 4 + r;  // C row=(lane>>4)*4+reg
      const float s0 = scales[grow * 2 + 0];
      const float s1 = scales[grow * 2 + 1];
      float* orow = out + (size_t)grow * N_TOT + n0 + wn * 64;
      #pragma unroll
      for (int j = 0; j < 4; ++j) {
        const float v0 = acc0[i][j][r] + bb0[j];
        const float v1 = acc1[i][j][r] + bb1[j];
        const float g0 = v0 / (1.0f + __expf(-v0));
        const float g1 = v1 / (1.0f + __expf(-v1));
        orow[j * 16 + fr] = s0 * g0 + s1 * g1;              // col = lane&15
      }
    }
  }
#undef STAGE_A
#undef STAGE_B0
#undef STAGE_B1
#undef FRAG
#undef BAR
#undef WAIT_VM
#undef SGB
#undef MFMA16
}

// ---------------------------------------------------------------------------
extern "C" void kernel_launch(void* const* d_in, const int* in_sizes, int n_in,
                              void* d_out, int out_size, void* d_ws, size_t ws_size,
                              hipStream_t stream)
{
  const float* tokens = (const float*)d_in[0];
  const float* gate_w = (const float*)d_in[1];
  const float* w0     = (const float*)d_in[2];
  const float* b0     = (const float*)d_in[3];
  const float* w1     = (const float*)d_in[4];
  const float* b1     = (const float*)d_in[5];
  float* out = (float*)d_out;

  char* ws = (char*)d_ws;
  u16* tok_bf = (u16*)ws;                                               // 32 MB
  u16* w0_bf  = (u16*)(ws + (size_t)M_TOT * K_TOT * 2);                 //  2 MB
  u16* w1_bf  = (u16*)(ws + (size_t)M_TOT * K_TOT * 2 + (size_t)N_TOT * K_TOT * 2);
  float* scales = (float*)(ws + (size_t)M_TOT * K_TOT * 2 + (size_t)2 * N_TOT * K_TOT * 2);

  gate_convert_kernel<<<GATE_BLOCKS + 2048, 256, 0, stream>>>(
      tokens, gate_w, w0, w1, tok_bf, w0_bf, w1_bf, scales);

  moe_gemm_kernel<<<(M_TOT/BM) * (N_TOT/BN), 512, 0, stream>>>(
      tok_bf, w0_bf, w1_bf, b0, b1, scales, out);
}